// Round 15
// baseline (125.193 us; speedup 1.0000x reference)
//
#include <hip/hip_runtime.h>
#include <hip/hip_bf16.h>
#include <cstdint>

// Problem constants
#define SDIM 160
#define HDIM 768
#define HALF 384
#define ODIM 260
#define OPAD 272           // 17 * 16
#define H0_ROWS 144        // m-half 0: tiles 0..8
#define H1_ROWS 128        // m-half 1: tiles 9..16
#define H0_BYTES 18432     // 8 kg * 144 rows * 16B per kc
// Workspace layout (bytes): pad@0(16) yb@16 Lb@245776 Rt@491536 W2b@737296
//                           W1b@1155088 end@3514384
#define WS_SMALL 1155088
#define WS_BIG   3514384

typedef __attribute__((ext_vector_type(8))) short short8;
typedef __attribute__((ext_vector_type(4))) float floatx4;
typedef _Float16 half8 __attribute__((ext_vector_type(8)));

typedef const __attribute__((address_space(1))) unsigned char gl_u8;
typedef __attribute__((address_space(3))) unsigned char lds_u8;

static __device__ __forceinline__ float bf2f(unsigned short u) {
    union { unsigned int i; float f; } v; v.i = ((unsigned int)u) << 16; return v.f;
}
static __device__ __forceinline__ unsigned short f2bf(float x) {
    __hip_bfloat16 h = __float2bfloat16(x);
    return *reinterpret_cast<unsigned short*>(&h);
}
static __device__ __forceinline__ unsigned short f2h(float x) {
    _Float16 h = (_Float16)x;
    return *reinterpret_cast<unsigned short*>(&h);
}
static __device__ __forceinline__ float q(float x) { return bf2f(f2bf(x)); }

// ---------------------------------------------------------------------------
// Kernel 1: RoPE(y) -> yb bf16; W2 -> W2b f16 half-major:
//   half0 @0:        [kg96][row 0..143][8]
//   half1 @96*144*8: [kg96][row 144..271][8]  (rows 260..271 zero)
// so each m-half block's per-kc chunk is one contiguous wave-linear span.
// (big path) W1 -> W1b bf16 [kg96][row1536][8].
// ---------------------------------------------------------------------------
__global__ __launch_bounds__(256) void prep_kernel(
    const float* __restrict__ y, const float* __restrict__ W1,
    const float* __restrict__ W2,
    unsigned short* __restrict__ yb, unsigned short* __restrict__ W2b,
    unsigned short* __restrict__ W1b, int do_w1b) {
    int bid = blockIdx.x;
    int t = threadIdx.x;
    if (bid < SDIM) {
        int s = bid;
        for (int p = t; p < HALF; p += 256) {
            float invf = __expf(-(2.0f * (float)p / (float)HDIM) * 9.210340371976184f);
            float th = (float)s * invf;
            float c = cosf(th), sn = sinf(th);
            float y0 = y[s * HDIM + 2 * p], y1 = y[s * HDIM + 2 * p + 1];
            yb[s * HDIM + 2 * p]     = f2bf(y0 * c - y1 * sn);
            yb[s * HDIM + 2 * p + 1] = f2bf(y1 * c + y0 * sn);
        }
    } else if (bid < SDIM + 102) {
        int idx = (bid - SDIM) * 256 + t;       // [0, 96*272)
        if (idx < 96 * OPAD) {
            int kg = idx % 96, row = idx / 96;
            unsigned short o8[8];
            if (row < ODIM) {
                float4 a = *reinterpret_cast<const float4*>(W2 + row * HDIM + kg * 8);
                float4 b = *reinterpret_cast<const float4*>(W2 + row * HDIM + kg * 8 + 4);
                o8[0] = f2h(a.x); o8[1] = f2h(a.y); o8[2] = f2h(a.z); o8[3] = f2h(a.w);
                o8[4] = f2h(b.x); o8[5] = f2h(b.y); o8[6] = f2h(b.z); o8[7] = f2h(b.w);
            } else {
                #pragma unroll
                for (int e = 0; e < 8; ++e) o8[e] = 0;
            }
            size_t dst = (row < H0_ROWS)
                ? ((size_t)kg * H0_ROWS + row)
                : ((size_t)96 * H0_ROWS + (size_t)kg * H1_ROWS + (row - H0_ROWS));
            *reinterpret_cast<uint4*>(W2b + dst * 8) =
                *reinterpret_cast<uint4*>(o8);
        }
    } else if (do_w1b) {
        int idx = (bid - SDIM - 102) * 256 + t; // [0, 96*1536)
        int kg = idx % 96, row = idx / 96;
        const float* src = (row < 768) ? (W1 + row * 1536 + kg * 8)
                                       : (W1 + (row - 768) * 1536 + 768 + kg * 8);
        float4 a = *reinterpret_cast<const float4*>(src);
        float4 b = *reinterpret_cast<const float4*>(src + 4);
        unsigned short o8[8];
        o8[0] = f2bf(a.x); o8[1] = f2bf(a.y); o8[2] = f2bf(a.z); o8[3] = f2bf(a.w);
        o8[4] = f2bf(b.x); o8[5] = f2bf(b.y); o8[6] = f2bf(b.z); o8[7] = f2bf(b.w);
        *reinterpret_cast<uint4*>(W1b + ((size_t)kg * 1536 + row) * 8) =
            *reinterpret_cast<uint4*>(o8);
    }
}

// ---------------------------------------------------------------------------
// Kernel 2 (lr3, proven): barrier-free L/R GEMM from W1b (L2).
// L stored [s][o] f16; R stored transposed Rt[kg][s][8] f16.
// ---------------------------------------------------------------------------
__global__ __launch_bounds__(64, 2) void lr3_kernel(
    const unsigned short* __restrict__ yb, const unsigned short* __restrict__ W1b,
    const float* __restrict__ b1,
    unsigned short* __restrict__ Lb, unsigned short* __restrict__ Rt) {
    int l = threadIdx.x & 63;
    int l16 = l & 15, qd = l >> 4;
    int mtb = blockIdx.x * 4;            // m-tile base [0,96)
    int sp = blockIdx.y;                 // s-pair [0,5)
    int s0 = sp * 32 + l16;
    int s1 = s0 + 16;

    floatx4 acc[2][4];
    #pragma unroll
    for (int st = 0; st < 2; ++st)
        #pragma unroll
        for (int mtl = 0; mtl < 4; ++mtl)
            acc[st][mtl] = (floatx4){0.0f, 0.0f, 0.0f, 0.0f};

    const unsigned short* yrow0 = yb + s0 * HDIM;
    const unsigned short* yrow1 = yb + s1 * HDIM;

    for (int ks = 0; ks < 24; ++ks) {
        int k = ks * 32 + qd * 8;
        int kg = ks * 4 + qd;
        union { uint4 u; short8 s; } bu0, bu1;
        bu0.u = *reinterpret_cast<const uint4*>(yrow0 + k);
        bu1.u = *reinterpret_cast<const uint4*>(yrow1 + k);
        #pragma unroll
        for (int mtl = 0; mtl < 4; ++mtl) {
            union { uint4 u; short8 s; } au;
            au.u = *reinterpret_cast<const uint4*>(
                W1b + ((size_t)kg * 1536 + (mtb + mtl) * 16 + l16) * 8);
            acc[0][mtl] = __builtin_amdgcn_mfma_f32_16x16x32_bf16(
                au.s, bu0.s, acc[0][mtl], 0, 0, 0);
            acc[1][mtl] = __builtin_amdgcn_mfma_f32_16x16x32_bf16(
                au.s, bu1.s, acc[1][mtl], 0, 0, 0);
        }
    }

    #pragma unroll
    for (int st = 0; st < 2; ++st) {
        int s_out = sp * 32 + st * 16 + l16;
        #pragma unroll
        for (int mtl = 0; mtl < 4; ++mtl) {
            int o2 = (mtb + mtl) * 16 + qd * 4;
            unsigned short out4[4];
            if (o2 < 768) {
                #pragma unroll
                for (int r = 0; r < 4; ++r) out4[r] = f2h(acc[st][mtl][r]);
                *reinterpret_cast<uint2*>(Lb + s_out * HDIM + o2) =
                    *reinterpret_cast<uint2*>(out4);
            } else {
                int ob = o2 - 768;               // [0,768), aligned to 4
                #pragma unroll
                for (int r = 0; r < 4; ++r)
                    out4[r] = f2h(acc[st][mtl][r] + b1[ob + r]);
                *reinterpret_cast<uint2*>(
                    Rt + ((size_t)(ob >> 3) * SDIM + s_out) * 8 + (ob & 7)) =
                    *reinterpret_cast<uint2*>(out4);
            }
        }
    }
}

// ---------------------------------------------------------------------------
// Kernel 3 (small-ws path only): pure-VALU L/R (f16; R transposed).
// ---------------------------------------------------------------------------
__global__ __launch_bounds__(256) void lr_fallback_kernel(
    const unsigned short* __restrict__ yb, const float* __restrict__ W1,
    const float* __restrict__ b1,
    unsigned short* __restrict__ Lb, unsigned short* __restrict__ Rt) {
    int idx = blockIdx.x * 256 + threadIdx.x;   // [0, 160*1536)
    int s = idx / 1536;
    int o2 = idx - s * 1536;
    const unsigned short* yrow = yb + s * HDIM;
    if (o2 < 768) {
        const float* wp = W1 + o2 * 1536;
        float a0 = 0.0f;
        for (int k = 0; k < HDIM; ++k) a0 += q(wp[k]) * bf2f(yrow[k]);
        Lb[s * HDIM + o2] = f2h(a0);
    } else {
        int ob = o2 - 768;
        const float* wp = W1 + ob * 1536 + 768;
        float a0 = 0.0f;
        for (int k = 0; k < HDIM; ++k) a0 += q(wp[k]) * bf2f(yrow[k]);
        Rt[((size_t)(ob >> 3) * SDIM + s) * 8 + (ob & 7)] = f2h(a0 + b1[ob]);
    }
}

// ---------------------------------------------------------------------------
// Kernel 4: out[rel,i,j,tag]=sigmoid(W2·relu(l_i+r_j)+b2).  f16 pair-GEMM.
// Grid (80,5,2): z = m-half (tiles 0..8 / 9..16). Block = 8 waves (512 thr)
// = 2 j-halves x 4 m-quarters of the half (2/2/2/3 or 2/2/2/2 tiles).
// Per-buffer LDS = half-chunk (18.4/16.4 KB), double-buffered -> 36.9 KB,
// 4 blocks/CU; 6400 waves total (2x r14). Same total ds_read + staging.
// Same K-order per accumulator as r13/r14 -> bit-identical output.
// ---------------------------------------------------------------------------
__global__ __launch_bounds__(512) void main_kernel(
    const unsigned short* __restrict__ Lb, const unsigned short* __restrict__ Rt,
    const unsigned short* __restrict__ W2b,
    const float* __restrict__ b2, float* __restrict__ out) {
    __shared__ __align__(16) unsigned char lds[2 * H0_BYTES];

    int w = threadIdx.x >> 6;        // 0..7
    int l = threadIdx.x & 63;
    int l16 = l & 15, qd = l >> 4;
    int jh = w & 1;                  // j-half
    int mq = w >> 1;                 // m-quarter within the half
    int h = blockIdx.z;              // m-half
    int nrows = h ? H1_ROWS : H0_ROWS;
    int hb = nrows * 128;            // bytes per kc chunk (8 kg * nrows * 16)
    int nseg = nrows >> 3;           // 1KB segments per chunk (18 or 16)
    int mt0l = mq * 2;               // local tile base
    int nmt = (h == 0 && mq == 3) ? 3 : 2;
    int mtg0 = h * 9;                // global tile base of this half
    int i0 = blockIdx.x * 2;
    int j = blockIdx.y * 32 + jh * 16 + l16;

    floatx4 acc[2][3];
    #pragma unroll
    for (int c = 0; c < 2; ++c)
        #pragma unroll
        for (int mtl = 0; mtl < 3; ++mtl)
            acc[c][mtl] = (floatx4){0.0f, 0.0f, 0.0f, 0.0f};

    const unsigned short* Lrow0 = Lb + i0 * HDIM;
    const unsigned short* Lrow1 = Lb + (i0 + 1) * HDIM;
    const unsigned char* wbase = reinterpret_cast<const unsigned char*>(W2b)
        + (h ? (size_t)96 * H0_ROWS * 16 : 0);

    // Stage chunk 0 into buffer 0. Wave w handles segments w, w+8, w+16.
    #pragma unroll
    for (int it = 0; it < 3; ++it) {
        int seg = w + it * 8;
        if (seg < nseg) {
            __builtin_amdgcn_global_load_lds(
                (gl_u8*)(wbase + seg * 1024 + l * 16),
                (lds_u8*)(lds + seg * 1024), 16, 0, 0);
        }
    }
    __syncthreads();

    for (int kc = 0; kc < 12; ++kc) {
        int buf = kc & 1;
        // Prefetch chunk kc+1 into the other buffer (overlaps compute of kc).
        if (kc < 11) {
            const unsigned char* gsrc = wbase + (size_t)(kc + 1) * hb;
            unsigned char* ldst = lds + (1 - buf) * hb;
            #pragma unroll
            for (int it = 0; it < 3; ++it) {
                int seg = w + it * 8;
                if (seg < nseg) {
                    __builtin_amdgcn_global_load_lds(
                        (gl_u8*)(gsrc + seg * 1024 + l * 16),
                        (lds_u8*)(ldst + seg * 1024), 16, 0, 0);
                }
            }
        }
        #pragma unroll
        for (int ks = 0; ks < 2; ++ks) {
            int k = kc * 64 + ks * 32 + qd * 8;
            int kg = kc * 8 + ks * 4 + qd;
            half8 bfrag[2];
            union { uint4 u; half8 h; } ru;
            ru.u = *reinterpret_cast<const uint4*>(
                Rt + ((size_t)kg * SDIM + j) * 8);
            #pragma unroll
            for (int c = 0; c < 2; ++c) {
                const unsigned short* Lr = c ? Lrow1 : Lrow0;
                union { uint4 u; half8 h; } lu;
                lu.u = *reinterpret_cast<const uint4*>(Lr + k);
                half8 hv = lu.h + ru.h;          // v_pk_add_f16
                #pragma unroll
                for (int e = 0; e < 8; ++e)      // v_pk_max_f16
                    hv[e] = hv[e] > (_Float16)0.0f ? hv[e] : (_Float16)0.0f;
                bfrag[c] = hv;
            }
            int ldsbase = buf * hb + ((ks * 4 + qd) * nrows + mt0l * 16 + l16) * 16;
            #pragma unroll
            for (int mtl = 0; mtl < 3; ++mtl) {
                if (mtl < nmt) {
                    union { uint4 u; half8 h; } au;
                    au.u = *reinterpret_cast<const uint4*>(
                        lds + ldsbase + mtl * 256);
                    acc[0][mtl] = __builtin_amdgcn_mfma_f32_16x16x32_f16(
                        au.h, bfrag[0], acc[0][mtl], 0, 0, 0);
                    acc[1][mtl] = __builtin_amdgcn_mfma_f32_16x16x32_f16(
                        au.h, bfrag[1], acc[1][mtl], 0, 0, 0);
                }
            }
        }
        __syncthreads();   // prefetch landed + reads of buf done
    }

    #pragma unroll
    for (int c = 0; c < 2; ++c) {
        int i = i0 + c;
        #pragma unroll
        for (int mtl = 0; mtl < 3; ++mtl) {
            if (mtl < nmt) {
                int ob = (mtg0 + mt0l + mtl) * 16 + qd * 4;
                if (ob < ODIM) {
                    float4 bv = *reinterpret_cast<const float4*>(b2 + ob);
                    int rel = ob >> 2;
                    float4 v;
                    v.x = 1.0f / (1.0f + __expf(-(acc[c][mtl][0] + bv.x)));
                    v.y = 1.0f / (1.0f + __expf(-(acc[c][mtl][1] + bv.y)));
                    v.z = 1.0f / (1.0f + __expf(-(acc[c][mtl][2] + bv.z)));
                    v.w = 1.0f / (1.0f + __expf(-(acc[c][mtl][3] + bv.w)));
                    *reinterpret_cast<float4*>(
                        out + (((rel * SDIM) + i) * SDIM + j) * 4) = v;
                }
            }
        }
    }
}

__global__ void ws_too_small_kernel(float* out) { out[0] = 999.0f; }

extern "C" void kernel_launch(void* const* d_in, const int* in_sizes, int n_in,
                              void* d_out, int out_size, void* d_ws, size_t ws_size,
                              hipStream_t stream) {
    const float* y  = (const float*)d_in[0];
    // d_in[1] = event_idx : unused by the reference
    const float* W1 = (const float*)d_in[2];
    const float* b1 = (const float*)d_in[3];
    const float* W2 = (const float*)d_in[4];
    const float* b2 = (const float*)d_in[5];
    float* out = (float*)d_out;

    if (ws_size < (size_t)WS_SMALL) {
        ws_too_small_kernel<<<dim3(1), dim3(1), 0, stream>>>(out);
        return;
    }

    unsigned short* yb  = (unsigned short*)((char*)d_ws + 16);    // 160*768
    unsigned short* Lb  = yb + SDIM * HDIM;
    unsigned short* Rt  = Lb + SDIM * HDIM;                       // 96*160*8
    unsigned short* W2b = Rt + SDIM * HDIM;                       // 96*272*8
    unsigned short* W1b = W2b + 96 * OPAD * 8;                    // 96*1536*8

    if (ws_size >= (size_t)WS_BIG) {
        prep_kernel<<<dim3(SDIM + 102 + 576), dim3(256), 0, stream>>>(
            y, W1, W2, yb, W2b, W1b, 1);
        lr3_kernel<<<dim3(24, 5), dim3(64), 0, stream>>>(yb, W1b, b1, Lb, Rt);
        main_kernel<<<dim3(80, 5, 2), dim3(512), 0, stream>>>(Lb, Rt, W2b, b2, out);
    } else {
        prep_kernel<<<dim3(SDIM + 102), dim3(256), 0, stream>>>(
            y, W1, W2, yb, W2b, W1b, 0);
        lr_fallback_kernel<<<dim3(960), dim3(256), 0, stream>>>(yb, W1, b1, Lb, Rt);
        main_kernel<<<dim3(80, 5, 2), dim3(512), 0, stream>>>(Lb, Rt, W2b, b2, out);
    }
}

// Round 16
// 118.047 us; speedup vs baseline: 1.0605x; 1.0605x over previous
//
#include <hip/hip_runtime.h>
#include <hip/hip_bf16.h>
#include <cstdint>

// Problem constants
#define SDIM 160
#define HDIM 768
#define HALF 384
#define ODIM 260
#define OPAD 272           // 17 * 16
#define CHUNK_BYTES 34816  // 8 kgroups * 272 rows * 16B (W2b chunk)
// Workspace layout (bytes): pad@0(16) yb@16 Lb@245776 Rt@491536 W2b@737296
//                           W1b@1155088 end@3514384
#define WS_SMALL 1155088
#define WS_BIG   3514384

typedef __attribute__((ext_vector_type(8))) short short8;
typedef __attribute__((ext_vector_type(4))) float floatx4;
typedef _Float16 half8 __attribute__((ext_vector_type(8)));

typedef const __attribute__((address_space(1))) unsigned char gl_u8;
typedef __attribute__((address_space(3))) unsigned char lds_u8;

static __device__ __forceinline__ float bf2f(unsigned short u) {
    union { unsigned int i; float f; } v; v.i = ((unsigned int)u) << 16; return v.f;
}
static __device__ __forceinline__ unsigned short f2bf(float x) {
    __hip_bfloat16 h = __float2bfloat16(x);
    return *reinterpret_cast<unsigned short*>(&h);
}
static __device__ __forceinline__ unsigned short f2h(float x) {
    _Float16 h = (_Float16)x;
    return *reinterpret_cast<unsigned short*>(&h);
}
static __device__ __forceinline__ float q(float x) { return bf2f(f2bf(x)); }

// ---------------------------------------------------------------------------
// Kernel 1: RoPE(y) -> yb bf16; W2 -> W2b f16 [kg96][row272][8] (pad rows 0);
// (big path) W1 -> W1b bf16 [kg96][row1536][8] (row<768 = L-half, >=768 = R).
// ---------------------------------------------------------------------------
__global__ __launch_bounds__(256) void prep_kernel(
    const float* __restrict__ y, const float* __restrict__ W1,
    const float* __restrict__ W2,
    unsigned short* __restrict__ yb, unsigned short* __restrict__ W2b,
    unsigned short* __restrict__ W1b, int do_w1b) {
    int bid = blockIdx.x;
    int t = threadIdx.x;
    if (bid < SDIM) {
        int s = bid;
        for (int p = t; p < HALF; p += 256) {
            float invf = __expf(-(2.0f * (float)p / (float)HDIM) * 9.210340371976184f);
            float th = (float)s * invf;
            float c = cosf(th), sn = sinf(th);
            float y0 = y[s * HDIM + 2 * p], y1 = y[s * HDIM + 2 * p + 1];
            yb[s * HDIM + 2 * p]     = f2bf(y0 * c - y1 * sn);
            yb[s * HDIM + 2 * p + 1] = f2bf(y1 * c + y0 * sn);
        }
    } else if (bid < SDIM + 102) {
        int idx = (bid - SDIM) * 256 + t;       // [0, 96*272)
        if (idx < 96 * OPAD) {
            int kg = idx % 96, row = idx / 96;
            unsigned short o8[8];
            if (row < ODIM) {
                float4 a = *reinterpret_cast<const float4*>(W2 + row * HDIM + kg * 8);
                float4 b = *reinterpret_cast<const float4*>(W2 + row * HDIM + kg * 8 + 4);
                o8[0] = f2h(a.x); o8[1] = f2h(a.y); o8[2] = f2h(a.z); o8[3] = f2h(a.w);
                o8[4] = f2h(b.x); o8[5] = f2h(b.y); o8[6] = f2h(b.z); o8[7] = f2h(b.w);
            } else {
                #pragma unroll
                for (int e = 0; e < 8; ++e) o8[e] = 0;
            }
            *reinterpret_cast<uint4*>(W2b + ((size_t)kg * OPAD + row) * 8) =
                *reinterpret_cast<uint4*>(o8);
        }
    } else if (do_w1b) {
        int idx = (bid - SDIM - 102) * 256 + t; // [0, 96*1536)
        int kg = idx % 96, row = idx / 96;
        const float* src = (row < 768) ? (W1 + row * 1536 + kg * 8)
                                       : (W1 + (row - 768) * 1536 + 768 + kg * 8);
        float4 a = *reinterpret_cast<const float4*>(src);
        float4 b = *reinterpret_cast<const float4*>(src + 4);
        unsigned short o8[8];
        o8[0] = f2bf(a.x); o8[1] = f2bf(a.y); o8[2] = f2bf(a.z); o8[3] = f2bf(a.w);
        o8[4] = f2bf(b.x); o8[5] = f2bf(b.y); o8[6] = f2bf(b.z); o8[7] = f2bf(b.w);
        *reinterpret_cast<uint4*>(W1b + ((size_t)kg * 1536 + row) * 8) =
            *reinterpret_cast<uint4*>(o8);
    }
}

// ---------------------------------------------------------------------------
// Kernel 2 (lr3, proven): barrier-free L/R GEMM from W1b (L2).
// L stored [s][o] f16 (row-major); R stored TRANSPOSED Rt[kg][s][8] f16 so
// main's R-read is contiguous across lanes (was a 16-row gather).
// ---------------------------------------------------------------------------
__global__ __launch_bounds__(64, 2) void lr3_kernel(
    const unsigned short* __restrict__ yb, const unsigned short* __restrict__ W1b,
    const float* __restrict__ b1,
    unsigned short* __restrict__ Lb, unsigned short* __restrict__ Rt) {
    int l = threadIdx.x & 63;
    int l16 = l & 15, qd = l >> 4;
    int mtb = blockIdx.x * 4;            // m-tile base [0,96)
    int sp = blockIdx.y;                 // s-pair [0,5)
    int s0 = sp * 32 + l16;
    int s1 = s0 + 16;

    floatx4 acc[2][4];
    #pragma unroll
    for (int st = 0; st < 2; ++st)
        #pragma unroll
        for (int mtl = 0; mtl < 4; ++mtl)
            acc[st][mtl] = (floatx4){0.0f, 0.0f, 0.0f, 0.0f};

    const unsigned short* yrow0 = yb + s0 * HDIM;
    const unsigned short* yrow1 = yb + s1 * HDIM;

    for (int ks = 0; ks < 24; ++ks) {
        int k = ks * 32 + qd * 8;
        int kg = ks * 4 + qd;
        union { uint4 u; short8 s; } bu0, bu1;
        bu0.u = *reinterpret_cast<const uint4*>(yrow0 + k);
        bu1.u = *reinterpret_cast<const uint4*>(yrow1 + k);
        #pragma unroll
        for (int mtl = 0; mtl < 4; ++mtl) {
            union { uint4 u; short8 s; } au;
            au.u = *reinterpret_cast<const uint4*>(
                W1b + ((size_t)kg * 1536 + (mtb + mtl) * 16 + l16) * 8);
            acc[0][mtl] = __builtin_amdgcn_mfma_f32_16x16x32_bf16(
                au.s, bu0.s, acc[0][mtl], 0, 0, 0);
            acc[1][mtl] = __builtin_amdgcn_mfma_f32_16x16x32_bf16(
                au.s, bu1.s, acc[1][mtl], 0, 0, 0);
        }
    }

    #pragma unroll
    for (int st = 0; st < 2; ++st) {
        int s_out = sp * 32 + st * 16 + l16;
        #pragma unroll
        for (int mtl = 0; mtl < 4; ++mtl) {
            int o2 = (mtb + mtl) * 16 + qd * 4;
            unsigned short out4[4];
            if (o2 < 768) {
                #pragma unroll
                for (int r = 0; r < 4; ++r) out4[r] = f2h(acc[st][mtl][r]);
                *reinterpret_cast<uint2*>(Lb + s_out * HDIM + o2) =
                    *reinterpret_cast<uint2*>(out4);
            } else {
                int ob = o2 - 768;               // [0,768), aligned to 4
                #pragma unroll
                for (int r = 0; r < 4; ++r)
                    out4[r] = f2h(acc[st][mtl][r] + b1[ob + r]);
                // Rt[kg=ob>>3][s][e=ob&7], 4 consecutive e -> uint2 store
                *reinterpret_cast<uint2*>(
                    Rt + ((size_t)(ob >> 3) * SDIM + s_out) * 8 + (ob & 7)) =
                    *reinterpret_cast<uint2*>(out4);
            }
        }
    }
}

// ---------------------------------------------------------------------------
// Kernel 3 (small-ws path only): pure-VALU L/R (f16; R transposed).
// ---------------------------------------------------------------------------
__global__ __launch_bounds__(256) void lr_fallback_kernel(
    const unsigned short* __restrict__ yb, const float* __restrict__ W1,
    const float* __restrict__ b1,
    unsigned short* __restrict__ Lb, unsigned short* __restrict__ Rt) {
    int idx = blockIdx.x * 256 + threadIdx.x;   // [0, 160*1536)
    int s = idx / 1536;
    int o2 = idx - s * 1536;
    const unsigned short* yrow = yb + s * HDIM;
    if (o2 < 768) {
        const float* wp = W1 + o2 * 1536;
        float a0 = 0.0f;
        for (int k = 0; k < HDIM; ++k) a0 += q(wp[k]) * bf2f(yrow[k]);
        Lb[s * HDIM + o2] = f2h(a0);
    } else {
        int ob = o2 - 768;
        const float* wp = W1 + ob * 1536 + 768;
        float a0 = 0.0f;
        for (int k = 0; k < HDIM; ++k) a0 += q(wp[k]) * bf2f(yrow[k]);
        Rt[((size_t)(ob >> 3) * SDIM + s) * 8 + (ob & 7)] = f2h(a0 + b1[ob]);
    }
}

// ---------------------------------------------------------------------------
// Kernel 4 (r14, best measured: 118.5 us total): f16 pair-GEMM.
// Block = 8 waves (512 thr) = 2 j-halves x 4 m-quarters; 2 i x 32 j per
// block. LDS double-buffer via global_load_lds (chunk kc+1 staged during
// compute of kc). R read from transposed Rt -> contiguous 256B per quad.
// Grid (80,5) = 400 blocks, 3200 waves.
// NOTE r15's m-half grid-split (z=2, half-chunks, 6400 waves) REGRESSED to
// 125.2 us: duplicated h-build VALU + non-uniform addressing outweighed the
// occupancy gain. Keep this shape.
// ---------------------------------------------------------------------------
__global__ __launch_bounds__(512) void main_kernel(
    const unsigned short* __restrict__ Lb, const unsigned short* __restrict__ Rt,
    const unsigned short* __restrict__ W2b,
    const float* __restrict__ b2, float* __restrict__ out) {
    __shared__ __align__(16) unsigned char lds[2 * CHUNK_BYTES];

    int w = threadIdx.x >> 6;        // 0..7
    int l = threadIdx.x & 63;
    int l16 = l & 15, qd = l >> 4;
    int jh = w & 1;                  // j-half
    int mq = w >> 1;                 // m-quarter
    int mt0 = mq * 4;
    int nmt = (mq == 3) ? 5 : 4;     // m-split 4/4/4/5 (17 tiles)
    int i0 = blockIdx.x * 2;
    int j = blockIdx.y * 32 + jh * 16 + l16;

    floatx4 acc[2][5];
    #pragma unroll
    for (int c = 0; c < 2; ++c)
        #pragma unroll
        for (int mtl = 0; mtl < 5; ++mtl)
            acc[c][mtl] = (floatx4){0.0f, 0.0f, 0.0f, 0.0f};

    const unsigned short* Lrow0 = Lb + i0 * HDIM;
    const unsigned short* Lrow1 = Lb + (i0 + 1) * HDIM;
    const unsigned char* wsrc = reinterpret_cast<const unsigned char*>(W2b);

    // Stage chunk 0 into buffer 0. Wave w handles segments w, w+8, ... (<34).
    #pragma unroll
    for (int it = 0; it < 5; ++it) {
        int seg = w + it * 8;
        if (seg < 34) {
            __builtin_amdgcn_global_load_lds(
                (gl_u8*)(wsrc + seg * 1024 + l * 16),
                (lds_u8*)(lds + seg * 1024), 16, 0, 0);
        }
    }
    __syncthreads();

    for (int kc = 0; kc < 12; ++kc) {
        int buf = kc & 1;
        // Prefetch chunk kc+1 into the other buffer (async, overlaps compute).
        if (kc < 11) {
            const unsigned char* gsrc = wsrc + (kc + 1) * CHUNK_BYTES;
            unsigned char* ldst = lds + (1 - buf) * CHUNK_BYTES;
            #pragma unroll
            for (int it = 0; it < 5; ++it) {
                int seg = w + it * 8;
                if (seg < 34) {
                    __builtin_amdgcn_global_load_lds(
                        (gl_u8*)(gsrc + seg * 1024 + l * 16),
                        (lds_u8*)(ldst + seg * 1024), 16, 0, 0);
                }
            }
        }
        #pragma unroll
        for (int ks = 0; ks < 2; ++ks) {
            int k = kc * 64 + ks * 32 + qd * 8;
            int kg = kc * 8 + ks * 4 + qd;
            half8 bfrag[2];
            // R read: contiguous across lanes (Rt[kg][j][8])
            union { uint4 u; half8 h; } ru;
            ru.u = *reinterpret_cast<const uint4*>(
                Rt + ((size_t)kg * SDIM + j) * 8);
            #pragma unroll
            for (int c = 0; c < 2; ++c) {
                const unsigned short* Lr = c ? Lrow1 : Lrow0;
                union { uint4 u; half8 h; } lu;
                lu.u = *reinterpret_cast<const uint4*>(Lr + k);
                half8 hv = lu.h + ru.h;          // v_pk_add_f16
                #pragma unroll
                for (int e = 0; e < 8; ++e)      // v_pk_max_f16
                    hv[e] = hv[e] > (_Float16)0.0f ? hv[e] : (_Float16)0.0f;
                bfrag[c] = hv;
            }
            int ldsbase = buf * CHUNK_BYTES + ((ks * 4 + qd) * OPAD + l16) * 16;
            #pragma unroll
            for (int mtl = 0; mtl < 5; ++mtl) {
                if (mtl < nmt) {
                    union { uint4 u; half8 h; } au;
                    au.u = *reinterpret_cast<const uint4*>(
                        lds + ldsbase + (mt0 + mtl) * 256);
                    acc[0][mtl] = __builtin_amdgcn_mfma_f32_16x16x32_f16(
                        au.h, bfrag[0], acc[0][mtl], 0, 0, 0);
                    acc[1][mtl] = __builtin_amdgcn_mfma_f32_16x16x32_f16(
                        au.h, bfrag[1], acc[1][mtl], 0, 0, 0);
                }
            }
        }
        __syncthreads();   // prefetch landed + reads of buf done
    }

    #pragma unroll
    for (int c = 0; c < 2; ++c) {
        int i = i0 + c;
        #pragma unroll
        for (int mtl = 0; mtl < 5; ++mtl) {
            if (mtl < nmt) {
                int ob = (mt0 + mtl) * 16 + qd * 4;
                if (ob < ODIM) {
                    float4 bv = *reinterpret_cast<const float4*>(b2 + ob);
                    int rel = ob >> 2;
                    float4 v;
                    v.x = 1.0f / (1.0f + __expf(-(acc[c][mtl][0] + bv.x)));
                    v.y = 1.0f / (1.0f + __expf(-(acc[c][mtl][1] + bv.y)));
                    v.z = 1.0f / (1.0f + __expf(-(acc[c][mtl][2] + bv.z)));
                    v.w = 1.0f / (1.0f + __expf(-(acc[c][mtl][3] + bv.w)));
                    *reinterpret_cast<float4*>(
                        out + (((rel * SDIM) + i) * SDIM + j) * 4) = v;
                }
            }
        }
    }
}

__global__ void ws_too_small_kernel(float* out) { out[0] = 999.0f; }

extern "C" void kernel_launch(void* const* d_in, const int* in_sizes, int n_in,
                              void* d_out, int out_size, void* d_ws, size_t ws_size,
                              hipStream_t stream) {
    const float* y  = (const float*)d_in[0];
    // d_in[1] = event_idx : unused by the reference
    const float* W1 = (const float*)d_in[2];
    const float* b1 = (const float*)d_in[3];
    const float* W2 = (const float*)d_in[4];
    const float* b2 = (const float*)d_in[5];
    float* out = (float*)d_out;

    if (ws_size < (size_t)WS_SMALL) {
        ws_too_small_kernel<<<dim3(1), dim3(1), 0, stream>>>(out);
        return;
    }

    unsigned short* yb  = (unsigned short*)((char*)d_ws + 16);    // 160*768
    unsigned short* Lb  = yb + SDIM * HDIM;
    unsigned short* Rt  = Lb + SDIM * HDIM;                       // 96*160*8
    unsigned short* W2b = Rt + SDIM * HDIM;                       // 96*272*8
    unsigned short* W1b = W2b + 96 * OPAD * 8;                    // 96*1536*8

    if (ws_size >= (size_t)WS_BIG) {
        prep_kernel<<<dim3(SDIM + 102 + 576), dim3(256), 0, stream>>>(
            y, W1, W2, yb, W2b, W1b, 1);
        lr3_kernel<<<dim3(24, 5), dim3(64), 0, stream>>>(yb, W1b, b1, Lb, Rt);
        main_kernel<<<dim3(80, 5), dim3(512), 0, stream>>>(Lb, Rt, W2b, b2, out);
    } else {
        prep_kernel<<<dim3(SDIM + 102), dim3(256), 0, stream>>>(
            y, W1, W2, yb, W2b, W1b, 0);
        lr_fallback_kernel<<<dim3(960), dim3(256), 0, stream>>>(yb, W1, b1, Lb, Rt);
        main_kernel<<<dim3(80, 5), dim3(512), 0, stream>>>(Lb, Rt, W2b, b2, out);
    }
}